// Round 1
// baseline (338.106 us; speedup 1.0000x reference)
//
#include <hip/hip_runtime.h>
#include <cfloat>
#include <cmath>

#define CCH 256   // channels
#define HID 16    // hidden = C / R

// One block per graph (grid-stride over graphs). Segment ids are sorted, so
// each graph is a contiguous node range found by binary search. Block:
//  - streams its segment with float4 loads, accumulating sum+max per channel
//  - LDS reduction across the 8 row-groups
//  - tiny fused MLP: att[g][c] = sigmoid((relu(avg@W1+b1)+relu(max@W1+b1))@W2 + 2*b2)
__global__ __launch_bounds__(512) void pool_mlp_kernel(
    const float* __restrict__ x, const int* __restrict__ seg,
    const int* __restrict__ numg,
    const float* __restrict__ W1, const float* __restrict__ b1,
    const float* __restrict__ W2, const float* __restrict__ b2,
    float* __restrict__ att, int N)
{
    const int G = *numg;
    const int tid = threadIdx.x;
    const int c4  = tid & 63;   // which float4 of the 256-channel row
    const int r   = tid >> 6;   // row group 0..7

    __shared__ float4 lsum[512];
    __shared__ float4 lmax[512];
    __shared__ float  avgp[CCH];
    __shared__ float  maxp[CCH];
    __shared__ float  ht[2 * HID];

    for (int g = (int)blockIdx.x; g < G; g += (int)gridDim.x) {
        // lower_bound(seg, g) and lower_bound(seg, g+1): segment is [start, end)
        int lo = 0, hi = N;
        while (lo < hi) { int mid = (lo + hi) >> 1; if (seg[mid] < g) lo = mid + 1; else hi = mid; }
        const int start = lo;
        hi = N;
        while (lo < hi) { int mid = (lo + hi) >> 1; if (seg[mid] < g + 1) lo = mid + 1; else hi = mid; }
        const int end = lo;
        const int count = end - start;

        float4 s = make_float4(0.f, 0.f, 0.f, 0.f);
        float4 m = make_float4(-FLT_MAX, -FLT_MAX, -FLT_MAX, -FLT_MAX);
        for (int n = start + r; n < end; n += 8) {
            const float4 v = *reinterpret_cast<const float4*>(x + (size_t)n * CCH + c4 * 4);
            s.x += v.x; s.y += v.y; s.z += v.z; s.w += v.w;
            m.x = fmaxf(m.x, v.x); m.y = fmaxf(m.y, v.y);
            m.z = fmaxf(m.z, v.z); m.w = fmaxf(m.w, v.w);
        }
        lsum[tid] = s; lmax[tid] = m;
        __syncthreads();

        if (tid < 64) {
            float4 S = lsum[tid];
            float4 M = lmax[tid];
            #pragma unroll
            for (int k = 1; k < 8; ++k) {
                const float4 S2 = lsum[tid + 64 * k];
                const float4 M2 = lmax[tid + 64 * k];
                S.x += S2.x; S.y += S2.y; S.z += S2.z; S.w += S2.w;
                M.x = fmaxf(M.x, M2.x); M.y = fmaxf(M.y, M2.y);
                M.z = fmaxf(M.z, M2.z); M.w = fmaxf(M.w, M2.w);
            }
            const float inv = (count > 0) ? 1.0f / (float)count : 0.0f;
            avgp[4 * tid + 0] = S.x * inv;
            avgp[4 * tid + 1] = S.y * inv;
            avgp[4 * tid + 2] = S.z * inv;
            avgp[4 * tid + 3] = S.w * inv;
            maxp[4 * tid + 0] = (count > 0) ? M.x : 0.0f;
            maxp[4 * tid + 1] = (count > 0) ? M.y : 0.0f;
            maxp[4 * tid + 2] = (count > 0) ? M.z : 0.0f;
            maxp[4 * tid + 3] = (count > 0) ? M.w : 0.0f;
        }
        __syncthreads();

        // hidden layer: 32 threads, each one (pool, j) pair
        if (tid < 2 * HID) {
            const int j = tid & (HID - 1);
            const float* p = (tid < HID) ? avgp : maxp;
            float h = b1[j];
            #pragma unroll 4
            for (int c = 0; c < CCH; ++c) h = fmaf(p[c], W1[c * HID + j], h);
            ht[tid] = fmaxf(h, 0.0f);
        }
        __syncthreads();

        // output layer + sigmoid: thread c computes att[g][c]
        if (tid < CCH) {
            float acc = 2.0f * b2[tid];
            #pragma unroll
            for (int j = 0; j < HID; ++j)
                acc = fmaf(ht[j] + ht[HID + j], W2[j * CCH + tid], acc);
            att[(size_t)g * CCH + tid] = 1.0f / (1.0f + expf(-acc));
        }
        __syncthreads();  // protect LDS reuse on next grid-stride iteration
    }
}

// out[n][c] = x[n][c] * att[seg[n]][c], float4-vectorized grid-stride.
// One wave (64 lanes * float4) covers exactly one 256-channel row, so the
// seg[n] load is wave-uniform and att rows stay L1/L2-resident.
__global__ __launch_bounds__(256) void apply_att_kernel(
    const float* __restrict__ x, const int* __restrict__ seg,
    const float* __restrict__ att, float* __restrict__ out, int n4)
{
    const int stride = (int)(gridDim.x * blockDim.x);
    for (int i = (int)(blockIdx.x * blockDim.x + threadIdx.x); i < n4; i += stride) {
        const int n = i >> 6;          // node index (C/4 = 64 float4 per row)
        const int g = seg[n];
        const float4 a = reinterpret_cast<const float4*>(att)[(size_t)g * 64 + (i & 63)];
        const float4 v = reinterpret_cast<const float4*>(x)[i];
        float4 o;
        o.x = v.x * a.x; o.y = v.y * a.y; o.z = v.z * a.z; o.w = v.w * a.w;
        reinterpret_cast<float4*>(out)[i] = o;
    }
}

extern "C" void kernel_launch(void* const* d_in, const int* in_sizes, int n_in,
                              void* d_out, int out_size, void* d_ws, size_t ws_size,
                              hipStream_t stream) {
    const float* x    = (const float*)d_in[0];
    const int*   seg  = (const int*)d_in[1];   // sorted segment ids
    const int*   numg = (const int*)d_in[2];   // num_graphs scalar (device read)
    const float* W1   = (const float*)d_in[3]; // [C, H]
    const float* b1   = (const float*)d_in[4]; // [H]
    const float* W2   = (const float*)d_in[5]; // [H, C]
    const float* b2   = (const float*)d_in[6]; // [C]
    float* out = (float*)d_out;
    float* att = (float*)d_ws;                 // [G, C] attention rows

    const int N = in_sizes[1];                 // number of nodes
    // C is fixed at 256 (in_sizes[6]); kernels hardcode the row layout.

    pool_mlp_kernel<<<512, 512, 0, stream>>>(x, seg, numg, W1, b1, W2, b2, att, N);

    const int n4 = out_size / 4;               // total float4 elements
    apply_att_kernel<<<2048, 256, 0, stream>>>(x, seg, att, out, n4);
}

// Round 2
// 284.947 us; speedup vs baseline: 1.1866x; 1.1866x over previous
//
#include <hip/hip_runtime.h>
#include <cfloat>
#include <cmath>

#define CCH 256   // channels
#define HID 16    // hidden = C / R

typedef float f32x4 __attribute__((ext_vector_type(4)));

// One block per graph (grid-stride). Segment ids are sorted -> contiguous
// ranges found by binary search. Each block:
//   1. streams its segment (float4, 2 outstanding loads), sum+max per channel
//   2. LDS reduce -> avg/max pools
//   3. fused MLP: att = sigmoid((relu(avg@W1+b1)+relu(max@W1+b1))@W2 + 2*b2)
//   4. applies att to its own segment IN REVERSE ORDER so the re-read of x
//      hits L2/L3 (tail of segment was pooled most recently). Nontemporal
//      stores keep dead output data from evicting the pooled x lines.
__global__ __launch_bounds__(512) void fused_gca_kernel(
    const float* __restrict__ x, const int* __restrict__ seg,
    const int* __restrict__ numg,
    const float* __restrict__ W1, const float* __restrict__ b1,
    const float* __restrict__ W2, const float* __restrict__ b2,
    float* __restrict__ out, int N)
{
    const int G = *numg;
    const int tid = (int)threadIdx.x;
    const int c4  = tid & 63;   // lane: which float4 of the 256-ch row
    const int r   = tid >> 6;   // wave id 0..7 = row group

    __shared__ f32x4 lsum[512];
    __shared__ f32x4 lmax[512];
    __shared__ float pool2[2 * CCH];   // [0:256) avg, [256:512) max
    __shared__ float ht[2 * HID];
    __shared__ float attn[CCH];

    for (int g = (int)blockIdx.x; g < G; g += (int)gridDim.x) {
        // ---- segment bounds: lower_bound(g), lower_bound(g+1) ----
        int lo = 0, hi = N;
        while (lo < hi) { int mid = (lo + hi) >> 1; if (seg[mid] < g) lo = mid + 1; else hi = mid; }
        const int start = lo;
        hi = N;
        while (lo < hi) { int mid = (lo + hi) >> 1; if (seg[mid] <= g) lo = mid + 1; else hi = mid; }
        const int end = lo;
        const int count = end - start;

        // ---- phase 1: pooling stream (2 rows in flight per wave) ----
        f32x4 s = {0.f, 0.f, 0.f, 0.f};
        f32x4 m = {-FLT_MAX, -FLT_MAX, -FLT_MAX, -FLT_MAX};
        int n = start + r;
        for (; n + 8 < end; n += 16) {
            const f32x4 v0 = *reinterpret_cast<const f32x4*>(x + (size_t)n * CCH + c4 * 4);
            const f32x4 v1 = *reinterpret_cast<const f32x4*>(x + (size_t)(n + 8) * CCH + c4 * 4);
            s += v0; s += v1;
            m.x = fmaxf(fmaxf(m.x, v0.x), v1.x);
            m.y = fmaxf(fmaxf(m.y, v0.y), v1.y);
            m.z = fmaxf(fmaxf(m.z, v0.z), v1.z);
            m.w = fmaxf(fmaxf(m.w, v0.w), v1.w);
        }
        if (n < end) {
            const f32x4 v0 = *reinterpret_cast<const f32x4*>(x + (size_t)n * CCH + c4 * 4);
            s += v0;
            m.x = fmaxf(m.x, v0.x); m.y = fmaxf(m.y, v0.y);
            m.z = fmaxf(m.z, v0.z); m.w = fmaxf(m.w, v0.w);
        }
        lsum[tid] = s; lmax[tid] = m;
        __syncthreads();

        // ---- phase 2: cross-wave reduce (64 threads own 4 channels each) ----
        if (tid < 64) {
            f32x4 S = lsum[tid];
            f32x4 M = lmax[tid];
            #pragma unroll
            for (int k = 1; k < 8; ++k) {
                const f32x4 S2 = lsum[tid + 64 * k];
                const f32x4 M2 = lmax[tid + 64 * k];
                S += S2;
                M.x = fmaxf(M.x, M2.x); M.y = fmaxf(M.y, M2.y);
                M.z = fmaxf(M.z, M2.z); M.w = fmaxf(M.w, M2.w);
            }
            const float inv = (count > 0) ? 1.0f / (float)count : 0.0f;
            pool2[4 * tid + 0] = S.x * inv;
            pool2[4 * tid + 1] = S.y * inv;
            pool2[4 * tid + 2] = S.z * inv;
            pool2[4 * tid + 3] = S.w * inv;
            pool2[CCH + 4 * tid + 0] = (count > 0) ? M.x : 0.0f;
            pool2[CCH + 4 * tid + 1] = (count > 0) ? M.y : 0.0f;
            pool2[CCH + 4 * tid + 2] = (count > 0) ? M.z : 0.0f;
            pool2[CCH + 4 * tid + 3] = (count > 0) ? M.w : 0.0f;
        }
        __syncthreads();

        // ---- phase 3a: hidden layer, all 512 threads ----
        // 16 threads per (pool,j) pair; partial dot + 16-lane shuffle reduce.
        {
            const int pair = tid >> 4;        // 0..31: (pool = pair>>4, j = pair&15)
            const int sub  = tid & 15;
            const int j    = pair & (HID - 1);
            const float* p = pool2 + (pair >> 4) * CCH;
            float h = 0.f;
            #pragma unroll
            for (int c = sub; c < CCH; c += 16)
                h = fmaf(p[c], W1[c * HID + j], h);
            h += __shfl_xor(h, 8, 64);
            h += __shfl_xor(h, 4, 64);
            h += __shfl_xor(h, 2, 64);
            h += __shfl_xor(h, 1, 64);
            if (sub == 0) ht[pair] = fmaxf(h + b1[j], 0.0f);
        }
        __syncthreads();

        // ---- phase 3b: output layer + sigmoid ----
        if (tid < CCH) {
            float acc = 2.0f * b2[tid];
            #pragma unroll
            for (int j = 0; j < HID; ++j)
                acc = fmaf(ht[j] + ht[HID + j], W2[j * CCH + tid], acc);
            attn[tid] = 1.0f / (1.0f + expf(-acc));
        }
        __syncthreads();

        // ---- phase 4: apply, reverse order for L2/L3 reuse ----
        {
            const f32x4 a4 = *reinterpret_cast<const f32x4*>(attn + c4 * 4);
            const int rem = end - (start + r);
            if (rem > 0) {
                int k = ((rem + 7) >> 3) - 1;   // last row index for this wave
                for (; k >= 1; k -= 2) {
                    const size_t i0 = (size_t)(start + r + 8 * k) * CCH + c4 * 4;
                    const size_t i1 = (size_t)(start + r + 8 * (k - 1)) * CCH + c4 * 4;
                    const f32x4 v0 = *reinterpret_cast<const f32x4*>(x + i0);
                    const f32x4 v1 = *reinterpret_cast<const f32x4*>(x + i1);
                    __builtin_nontemporal_store(v0 * a4, reinterpret_cast<f32x4*>(out + i0));
                    __builtin_nontemporal_store(v1 * a4, reinterpret_cast<f32x4*>(out + i1));
                }
                if (k == 0) {
                    const size_t i0 = (size_t)(start + r) * CCH + c4 * 4;
                    const f32x4 v0 = *reinterpret_cast<const f32x4*>(x + i0);
                    __builtin_nontemporal_store(v0 * a4, reinterpret_cast<f32x4*>(out + i0));
                }
            }
        }
        __syncthreads();  // protect LDS reuse on next grid-stride iteration
    }
}

extern "C" void kernel_launch(void* const* d_in, const int* in_sizes, int n_in,
                              void* d_out, int out_size, void* d_ws, size_t ws_size,
                              hipStream_t stream) {
    const float* x    = (const float*)d_in[0];
    const int*   seg  = (const int*)d_in[1];   // sorted segment ids (int32)
    const int*   numg = (const int*)d_in[2];   // num_graphs scalar (device read)
    const float* W1   = (const float*)d_in[3]; // [C, H]
    const float* b1   = (const float*)d_in[4]; // [H]
    const float* W2   = (const float*)d_in[5]; // [H, C]
    const float* b2   = (const float*)d_in[6]; // [C]
    float* out = (float*)d_out;

    const int N = in_sizes[1];                 // number of nodes

    fused_gca_kernel<<<512, 512, 0, stream>>>(x, seg, numg, W1, b1, W2, b2, out, N);
}